// Round 10
// baseline (368.537 us; speedup 1.0000x reference)
//
#include <hip/hip_runtime.h>

// WaveNet gated residual block, MI355X bf16-MFMA implementation (v10).
// v10: cross-tile software pipeline (T14 async-stage). Each block owns TPB=4
// consecutive t-tiles; tile t+1's global loads are issued right after tile t's
// stage buffer is consumed, so their ~900cyc latency hides under k1+gate+k2.
// The reg->LDS write at the top of each iter hits already-landed data (vmcnt
// free). No weight persistence (v6's spill lesson): weights reload per tile,
// L2-hot. All sched_barrier(0) pins removed (m141: pinning defeats scheduler).
// Stage split: X loads issued after barrier A (span k1+gate+k2); cond loads
// issued after barrier B (span gate+k2) to cap live registers < 128.

#define NB 8
#define NT 16000
#define CIN 128
#define CCOND 80
#define CCP 96
#define TT 64
#define TPB 4

typedef __attribute__((ext_vector_type(8))) __bf16 bf16x8;
typedef __attribute__((ext_vector_type(4))) float f32x4;
typedef __attribute__((ext_vector_type(4))) unsigned short u16x4;
typedef __attribute__((ext_vector_type(4))) unsigned int u32x4;

__device__ __forceinline__ unsigned short f2bf(float f) {
  unsigned int u = __float_as_uint(f);
  return (unsigned short)((u + 0x7fffu + ((u >> 16) & 1u)) >> 16);  // RNE
}
__device__ __forceinline__ bf16x8 ldb8(const unsigned short* p) {
  return *reinterpret_cast<const bf16x8*>(p);
}

// ---- pack weights to bf16 [M][K] ----
__global__ void pack_weights(const float* __restrict__ wc, const float* __restrict__ wcd,
                             const float* __restrict__ wo, const float* __restrict__ wsk,
                             unsigned short* __restrict__ wpc,   // [256][384] k=tap*128+c
                             unsigned short* __restrict__ wpcd,  // [256][96]  zero-pad k>=80
                             unsigned short* __restrict__ wp2)   // [384][128] rows 0-127 Wout, 128-383 Wskip
{
  int idx = blockIdx.x * 256 + threadIdx.x;
  if (idx < 98304) {
    int o = idx / 384, k = idx - o * 384;
    int tap = k >> 7, c = k & 127;
    wpc[idx] = f2bf(wc[(o * 128 + c) * 3 + tap]);
  } else if (idx < 122880) {
    int i = idx - 98304;
    int o = i / 96, k = i - o * 96;
    wpcd[i] = f2bf(k < CCOND ? wcd[o * CCOND + k] : 0.f);
  } else if (idx < 172032) {
    int i = idx - 122880;
    int m = i >> 7, k = i & 127;
    wp2[i] = f2bf(m < 128 ? wo[m * 128 + k] : wsk[(m - 128) * 128 + k]);
  }
}

// ======================= FUSED transpose+k1+k2, pipelined (v10) ==============
__global__ __launch_bounds__(512, 4) void k12_fused(
    const unsigned short* __restrict__ wpc, const unsigned short* __restrict__ wpcd,
    const unsigned short* __restrict__ wp2,
    const float* __restrict__ in, const float* __restrict__ cond,
    const float* __restrict__ bconv, const float* __restrict__ bout,
    const float* __restrict__ bskip, float* __restrict__ out)
{
  __shared__ u32x4 ldsX_[1152];  // X tile [72 t-rows][16 ch-granules x 16B], swizzled
  __shared__ u32x4 ldsU_[1024];  // UNION: cond [64][12x16B] / z [64][16x16B], swizzled
  char* ldsX = (char*)ldsX_;
  char* ldsU = (char*)ldsU_;

  int b = blockIdx.y;
  int tbase = blockIdx.x * TPB;
  int ntiles = 250 - tbase; if (ntiles > TPB) ntiles = TPB;
  int tid = threadIdx.x;
  int lane = tid & 63, w = tid >> 6;            // w 0..7
  int l15 = lane & 15, g = lane >> 4;

  float sx[3][8], sc[2][8];

  // issue X loads for tile starting at t0n (lanes = consecutive t: coalesced)
  auto issue_x = [&](int t0n) {
    #pragma unroll
    for (int r = 0; r < 3; ++r) {
      int gi = r * 512 + tid;
      if (gi < 1152) {
        int gch = gi / 72, row = gi - gch * 72;
        int t = t0n - 8 + row;
        const float* src = &in[((size_t)b * CIN + gch * 8) * NT + t];
        #pragma unroll
        for (int p = 0; p < 8; ++p)
          sx[r][p] = (t >= 0) ? src[(size_t)p * NT] : 0.f;
      }
    }
  };
  auto issue_c = [&](int t0n) {
    #pragma unroll
    for (int r = 0; r < 2; ++r) {
      int gi = r * 512 + tid;
      if (gi < 768) {
        int gch = gi >> 6, row = gi & 63;
        if (gch < 10) {
          const float* src = &cond[((size_t)b * CCOND + gch * 8) * NT + t0n + row];
          #pragma unroll
          for (int p = 0; p < 8; ++p)
            sc[r][p] = src[(size_t)p * NT];
        }
      }
    }
  };
  auto write_stage = [&]() {
    #pragma unroll
    for (int r = 0; r < 3; ++r) {
      int gi = r * 512 + tid;
      if (gi < 1152) {
        int gch = gi / 72, row = gi - gch * 72;
        u32x4 pk;
        #pragma unroll
        for (int p = 0; p < 4; ++p)
          pk[p] = (unsigned)f2bf(sx[r][2 * p]) | ((unsigned)f2bf(sx[r][2 * p + 1]) << 16);
        *reinterpret_cast<u32x4*>(&ldsX[row * 256 + ((gch ^ (row & 7)) << 4)]) = pk;
      }
    }
    #pragma unroll
    for (int r = 0; r < 2; ++r) {
      int gi = r * 512 + tid;
      if (gi < 768) {
        int gch = gi >> 6, row = gi & 63;
        u32x4 pk = {};
        if (gch < 10) {
          #pragma unroll
          for (int p = 0; p < 4; ++p)
            pk[p] = (unsigned)f2bf(sc[r][2 * p]) | ((unsigned)f2bf(sc[r][2 * p + 1]) << 16);
        }
        *reinterpret_cast<u32x4*>(&ldsU[row * 192 + ((gch ^ (row & 3)) << 4)]) = pk;
      }
    }
  };

  int rt = 16 * w + l15, rs = 128 + 16 * w + l15;
  float* skipp = out + (size_t)NB * 128 * NT;

  // prologue: load tile 0 (latency exposed once per block)
  issue_x(tbase * TT);
  issue_c(tbase * TT);

  for (int it = 0; it < ntiles; ++it) {
    int t0 = (tbase + it) * TT;
    write_stage();                 // data landed long ago -> vmcnt free
    __syncthreads();               // (A) stage visible
    if (it + 1 < ntiles) issue_x(t0 + TT);   // latency spans k1+gate+k2

    // ---- k1: wave w owns rows 16w..16w+15 (tanh), 128+16w.. (sigmoid) ----
    f32x4 at[4] = {}, as_[4] = {};
    #pragma unroll
    for (int gg = 0; gg < 5; ++gg) {
      bf16x8 wt[3], wss[3];
      #pragma unroll
      for (int q = 0; q < 3; ++q) {
        int s = gg * 3 + q;
        if (s < 12) {
          int tap = s >> 2, kc = s & 3;
          wt[q]  = ldb8(&wpc[(size_t)rt * 384 + tap * 128 + kc * 32 + g * 8]);
          wss[q] = ldb8(&wpc[(size_t)rs * 384 + tap * 128 + kc * 32 + g * 8]);
        } else {
          int kc = s - 12;
          wt[q]  = ldb8(&wpcd[(size_t)rt * CCP + kc * 32 + g * 8]);
          wss[q] = ldb8(&wpcd[(size_t)rs * CCP + kc * 32 + g * 8]);
        }
      }
      #pragma unroll
      for (int q = 0; q < 3; ++q) {
        int s = gg * 3 + q;
        bf16x8 bfr[4];
        if (s < 12) {
          int tap = s >> 2, kc = s & 3;
          int ck = kc * 4 + g;
          #pragma unroll
          for (int nf = 0; nf < 4; ++nf) {
            int tl = nf * 16 + l15 + tap * 4;
            bfr[nf] = *reinterpret_cast<const bf16x8*>(&ldsX[tl * 256 + ((ck ^ (tl & 7)) << 4)]);
          }
        } else {
          int kc = s - 12;
          int ck = kc * 4 + g;
          #pragma unroll
          for (int nf = 0; nf < 4; ++nf) {
            int r = nf * 16 + l15;
            bfr[nf] = *reinterpret_cast<const bf16x8*>(&ldsU[r * 192 + ((ck ^ (r & 3)) << 4)]);
          }
        }
        #pragma unroll
        for (int nf = 0; nf < 4; ++nf) {
          at[nf]  = __builtin_amdgcn_mfma_f32_16x16x32_bf16(wt[q],  bfr[nf], at[nf],  0, 0, 0);
          as_[nf] = __builtin_amdgcn_mfma_f32_16x16x32_bf16(wss[q], bfr[nf], as_[nf], 0, 0, 0);
        }
      }
    }

    float btv[4], bsv[4];
    #pragma unroll
    for (int j = 0; j < 4; ++j) {
      btv[j] = bconv[16 * w + g * 4 + j];
      bsv[j] = bconv[128 + 16 * w + g * 4 + j];
    }

    // prefetch k2 weights mf=0 (latency hides under barrier+gate)
    bf16x8 wk2buf[2][4];
    #pragma unroll
    for (int kc = 0; kc < 4; ++kc)
      wk2buf[0][kc] = ldb8(&wp2[(size_t)(48 * w + l15) * 128 + kc * 32 + g * 8]);

    __syncthreads();               // (B) cond region consumed; ldsU becomes z
    if (it + 1 < ntiles) issue_c(t0 + TT);   // latency spans gate+k2

    // ---- gate in-register -> z into swizzled ldsU [64 rows][256B] ----
    {
      int cg = 2 * w + (g >> 1);
      int off = (g & 1) * 8;
      #pragma unroll
      for (int nf = 0; nf < 4; ++nf) {
        int tl = nf * 16 + l15;
        u16x4 pk;
        #pragma unroll
        for (int j = 0; j < 4; ++j) {
          float a = at[nf][j] + btv[j];
          float s = as_[nf][j] + bsv[j];
          float z = (1.f - 2.f / (1.f + __expf(2.f * a))) * (1.f / (1.f + __expf(-s)));
          pk[j] = f2bf(z);
        }
        *reinterpret_cast<u16x4*>(&ldsU[tl * 256 + ((cg ^ (tl & 7)) << 4) + off]) = pk;
      }
    }
    __syncthreads();               // (C) z visible

    // ---- k2 per-mf: compute 16 rows, store; prefetch next mf's weights ----
    #pragma unroll
    for (int mf = 0; mf < 3; ++mf) {
      bf16x8* wcur = wk2buf[mf & 1];
      bf16x8* wnx  = wk2buf[(mf + 1) & 1];
      if (mf < 2) {
        #pragma unroll
        for (int kc = 0; kc < 4; ++kc)
          wnx[kc] = ldb8(&wp2[(size_t)(48 * w + 16 * (mf + 1) + l15) * 128 + kc * 32 + g * 8]);
      }
      f32x4 am[4] = {};
      #pragma unroll
      for (int kc = 0; kc < 4; ++kc) {
        bf16x8 bfr[4];
        #pragma unroll
        for (int nf = 0; nf < 4; ++nf) {
          int r = nf * 16 + l15;
          bfr[nf] = *reinterpret_cast<const bf16x8*>(&ldsU[r * 256 + (((kc * 4 + g) ^ (r & 7)) << 4)]);
        }
        #pragma unroll
        for (int nf = 0; nf < 4; ++nf)
          am[nf] = __builtin_amdgcn_mfma_f32_16x16x32_bf16(wcur[kc], bfr[nf], am[nf], 0, 0, 0);
      }
      int mrow = 48 * w + 16 * mf + g * 4;
      #pragma unroll
      for (int j = 0; j < 4; ++j) {
        int m = mrow + j;
        float bv;
        float* basep;
        if (m < 128) { bv = bout[m];        basep = out   + ((size_t)b * 128 + m) * NT; }
        else         { bv = bskip[m - 128]; basep = skipp + ((size_t)b * 256 + (m - 128)) * NT; }
        #pragma unroll
        for (int nf = 0; nf < 4; ++nf)
          basep[t0 + nf * 16 + l15] = am[nf][j] + bv;
      }
    }
    __syncthreads();               // (D) tile done (z consumed; X re-writable)
  }
}

extern "C" void kernel_launch(void* const* d_in, const int* in_sizes, int n_in,
                              void* d_out, int out_size, void* d_ws, size_t ws_size,
                              hipStream_t stream)
{
  const float* input = (const float*)d_in[0];
  const float* cond  = (const float*)d_in[1];
  const float* wconv = (const float*)d_in[2];
  const float* bconv = (const float*)d_in[3];
  const float* wcond = (const float*)d_in[4];
  const float* wout  = (const float*)d_in[5];
  const float* boutp = (const float*)d_in[6];
  const float* wskip = (const float*)d_in[7];
  const float* bskip = (const float*)d_in[8];
  float* out = (float*)d_out;

  unsigned short* wpc  = (unsigned short*)d_ws;     //  98304 elems
  unsigned short* wpcd = wpc + 98304;               //  24576 elems
  unsigned short* wp2  = wpcd + 24576;              //  49152 elems

  pack_weights<<<672, 256, 0, stream>>>(wconv, wcond, wout, wskip, wpc, wpcd, wp2);
  k12_fused<<<dim3(63, NB), 512, 0, stream>>>(wpc, wpcd, wp2, input, cond,
                                              bconv, boutp, bskip, out);
}

// Round 11
// 106.353 us; speedup vs baseline: 3.4652x; 3.4652x over previous
//
#include <hip/hip_runtime.h>

// WaveNet gated residual block, MI355X bf16-MFMA implementation (v11).
// v11 = v9 structure (fused transpose+k1+gate+k2, single tile per block,
// no cross-tile reg pipeline -- v10 spilled 300MB to scratch) with TT=128:
// halve block count 2000->1000. Same total MFMA/traffic, but half the phase
// transitions/barriers, and each k1 weight fragment now feeds 16 MFMAs
// instead of 8 (B-tile nf 4->8). Tests the "per-block overhead" theory from
// the v4-v9 invariance (k12 ~15us/CU per 64-t tile regardless of variant).
// LDS: X[136 rows x 256B] + union(cond[128x192B] / z[128x256B]) = 67.6KB
// -> 2 blocks/CU. Peak live regs ~110 (acc 64 + weights 24 + misc) < 128.

#define NB 8
#define NT 16000
#define CIN 128
#define CCOND 80
#define CCP 96
#define TT 128
#define NROW 136   // TT + 8 halo

typedef __attribute__((ext_vector_type(8))) __bf16 bf16x8;
typedef __attribute__((ext_vector_type(4))) float f32x4;
typedef __attribute__((ext_vector_type(4))) unsigned short u16x4;
typedef __attribute__((ext_vector_type(4))) unsigned int u32x4;

__device__ __forceinline__ unsigned short f2bf(float f) {
  unsigned int u = __float_as_uint(f);
  return (unsigned short)((u + 0x7fffu + ((u >> 16) & 1u)) >> 16);  // RNE
}
__device__ __forceinline__ bf16x8 ldb8(const unsigned short* p) {
  return *reinterpret_cast<const bf16x8*>(p);
}

// ---- pack weights to bf16 [M][K] ----
__global__ void pack_weights(const float* __restrict__ wc, const float* __restrict__ wcd,
                             const float* __restrict__ wo, const float* __restrict__ wsk,
                             unsigned short* __restrict__ wpc,   // [256][384] k=tap*128+c
                             unsigned short* __restrict__ wpcd,  // [256][96]  zero-pad k>=80
                             unsigned short* __restrict__ wp2)   // [384][128] rows 0-127 Wout, 128-383 Wskip
{
  int idx = blockIdx.x * 256 + threadIdx.x;
  if (idx < 98304) {
    int o = idx / 384, k = idx - o * 384;
    int tap = k >> 7, c = k & 127;
    wpc[idx] = f2bf(wc[(o * 128 + c) * 3 + tap]);
  } else if (idx < 122880) {
    int i = idx - 98304;
    int o = i / 96, k = i - o * 96;
    wpcd[i] = f2bf(k < CCOND ? wcd[o * CCOND + k] : 0.f);
  } else if (idx < 172032) {
    int i = idx - 122880;
    int m = i >> 7, k = i & 127;
    wp2[i] = f2bf(m < 128 ? wo[m * 128 + k] : wsk[(m - 128) * 128 + k]);
  }
}

// ======================= FUSED transpose+k1+k2 (v11, TT=128) =================
__global__ __launch_bounds__(512, 4) void k12_fused(
    const unsigned short* __restrict__ wpc, const unsigned short* __restrict__ wpcd,
    const unsigned short* __restrict__ wp2,
    const float* __restrict__ in, const float* __restrict__ cond,
    const float* __restrict__ bconv, const float* __restrict__ bout,
    const float* __restrict__ bskip, float* __restrict__ out)
{
  __shared__ u32x4 ldsX_[2176];  // X tile [136 t-rows][16 granules x 16B], swizzled
  __shared__ u32x4 ldsU_[2048];  // UNION: cond [128][12x16B] / z [128][16x16B]
  char* ldsX = (char*)ldsX_;
  char* ldsU = (char*)ldsU_;

  int b = blockIdx.y;
  int t0 = blockIdx.x * TT;
  int tid = threadIdx.x;
  int lane = tid & 63, w = tid >> 6;            // w 0..7
  int l15 = lane & 15, g = lane >> 4;

  // ---- stage X from raw f32: task gi = gch*NROW + row (lanes = consecutive t) ----
  #pragma unroll
  for (int rep = 0; rep < 5; ++rep) {
    int gi = rep * 512 + tid;
    if (gi < 16 * NROW) {
      int gch = gi / NROW;                      // channel granule 0..15
      int row = gi - gch * NROW;                // t-local 0..135
      int t = t0 - 8 + row;
      u32x4 pk = {};
      if (t >= 0) {
        const float* src = &in[((size_t)b * CIN + gch * 8) * NT + t];
        #pragma unroll
        for (int p = 0; p < 4; ++p) {
          float v0 = src[(size_t)(2 * p) * NT];
          float v1 = src[(size_t)(2 * p + 1) * NT];
          pk[p] = (unsigned)f2bf(v0) | ((unsigned)f2bf(v1) << 16);
        }
      }
      *reinterpret_cast<u32x4*>(&ldsX[row * 256 + ((gch ^ (row & 7)) << 4)]) = pk;
    }
  }
  // ---- stage cond: task gi = gch*128 + row; granules 10,11 = zero pad ----
  #pragma unroll
  for (int rep = 0; rep < 3; ++rep) {
    int gi = rep * 512 + tid;                   // < 1536 always
    int gch = gi >> 7;                          // 0..11
    int row = gi & 127;
    u32x4 pk = {};
    if (gch < 10) {
      const float* src = &cond[((size_t)b * CCOND + gch * 8) * NT + t0 + row];
      #pragma unroll
      for (int p = 0; p < 4; ++p) {
        float v0 = src[(size_t)(2 * p) * NT];
        float v1 = src[(size_t)(2 * p + 1) * NT];
        pk[p] = (unsigned)f2bf(v0) | ((unsigned)f2bf(v1) << 16);
      }
    }
    *reinterpret_cast<u32x4*>(&ldsU[row * 192 + ((gch ^ (row & 3)) << 4)]) = pk;
  }
  __syncthreads();

  // ---- k1: wave w owns rows 16w..16w+15 (tanh) and 128+16w.. (sigmoid) ----
  int rt = 16 * w + l15, rs = 128 + 16 * w + l15;
  f32x4 at[8] = {}, as_[8] = {};

  #pragma unroll
  for (int gg = 0; gg < 5; ++gg) {
    bf16x8 wt[3], wss[3];
    #pragma unroll
    for (int q = 0; q < 3; ++q) {
      int s = gg * 3 + q;
      if (s < 12) {
        int tap = s >> 2, kc = s & 3;
        wt[q]  = ldb8(&wpc[(size_t)rt * 384 + tap * 128 + kc * 32 + g * 8]);
        wss[q] = ldb8(&wpc[(size_t)rs * 384 + tap * 128 + kc * 32 + g * 8]);
      } else {
        int kc = s - 12;
        wt[q]  = ldb8(&wpcd[(size_t)rt * CCP + kc * 32 + g * 8]);
        wss[q] = ldb8(&wpcd[(size_t)rs * CCP + kc * 32 + g * 8]);
      }
    }
    __builtin_amdgcn_sched_barrier(0);   // keep the load batch ahead of the MFMAs
    #pragma unroll
    for (int q = 0; q < 3; ++q) {
      int s = gg * 3 + q;
      if (s < 12) {
        int tap = s >> 2, kc = s & 3;
        int ck = kc * 4 + g;
        #pragma unroll
        for (int nf = 0; nf < 8; ++nf) {
          int tl = nf * 16 + l15 + tap * 4;
          bf16x8 bfr = *reinterpret_cast<const bf16x8*>(&ldsX[tl * 256 + ((ck ^ (tl & 7)) << 4)]);
          at[nf]  = __builtin_amdgcn_mfma_f32_16x16x32_bf16(wt[q],  bfr, at[nf],  0, 0, 0);
          as_[nf] = __builtin_amdgcn_mfma_f32_16x16x32_bf16(wss[q], bfr, as_[nf], 0, 0, 0);
        }
      } else {
        int kc = s - 12;
        int ck = kc * 4 + g;
        #pragma unroll
        for (int nf = 0; nf < 8; ++nf) {
          int r = nf * 16 + l15;
          bf16x8 bfr = *reinterpret_cast<const bf16x8*>(&ldsU[r * 192 + ((ck ^ (r & 3)) << 4)]);
          at[nf]  = __builtin_amdgcn_mfma_f32_16x16x32_bf16(wt[q],  bfr, at[nf],  0, 0, 0);
          as_[nf] = __builtin_amdgcn_mfma_f32_16x16x32_bf16(wss[q], bfr, as_[nf], 0, 0, 0);
        }
      }
    }
  }

  float btv[4], bsv[4];
  #pragma unroll
  for (int j = 0; j < 4; ++j) {
    btv[j] = bconv[16 * w + g * 4 + j];
    bsv[j] = bconv[128 + 16 * w + g * 4 + j];
  }

  // preload k2 weights mf=0 (latency hides under barrier+gate)
  bf16x8 wk2buf[2][4];
  #pragma unroll
  for (int kc = 0; kc < 4; ++kc)
    wk2buf[0][kc] = ldb8(&wp2[(size_t)(48 * w + l15) * 128 + kc * 32 + g * 8]);

  __syncthreads();   // cond region consumed; ldsU becomes z

  // ---- gate in-register -> z into swizzled ldsU [128 rows][256B] ----
  {
    int cg = 2 * w + (g >> 1);
    int off = (g & 1) * 8;
    #pragma unroll
    for (int nf = 0; nf < 8; ++nf) {
      int tl = nf * 16 + l15;
      u16x4 pk;
      #pragma unroll
      for (int j = 0; j < 4; ++j) {
        float a = at[nf][j] + btv[j];
        float s = as_[nf][j] + bsv[j];
        float z = (1.f - 2.f / (1.f + __expf(2.f * a))) * (1.f / (1.f + __expf(-s)));
        pk[j] = f2bf(z);
      }
      *reinterpret_cast<u16x4*>(&ldsU[tl * 256 + ((cg ^ (tl & 7)) << 4) + off]) = pk;
    }
  }
  __syncthreads();

  // ---- k2 per-mf: compute 16 rows, store; prefetch next mf's weights ----
  float* skipp = out + (size_t)NB * 128 * NT;
  #pragma unroll
  for (int mf = 0; mf < 3; ++mf) {
    bf16x8* wcur = wk2buf[mf & 1];
    bf16x8* wnx  = wk2buf[(mf + 1) & 1];
    if (mf < 2) {
      #pragma unroll
      for (int kc = 0; kc < 4; ++kc)
        wnx[kc] = ldb8(&wp2[(size_t)(48 * w + 16 * (mf + 1) + l15) * 128 + kc * 32 + g * 8]);
    }
    __builtin_amdgcn_sched_barrier(0);
    f32x4 am[8] = {};
    #pragma unroll
    for (int kc = 0; kc < 4; ++kc) {
      #pragma unroll
      for (int nf = 0; nf < 8; ++nf) {
        int r = nf * 16 + l15;
        bf16x8 bfr = *reinterpret_cast<const bf16x8*>(&ldsU[r * 256 + (((kc * 4 + g) ^ (r & 7)) << 4)]);
        am[nf] = __builtin_amdgcn_mfma_f32_16x16x32_bf16(wcur[kc], bfr, am[nf], 0, 0, 0);
      }
    }
    int mrow = 48 * w + 16 * mf + g * 4;
    #pragma unroll
    for (int j = 0; j < 4; ++j) {
      int m = mrow + j;
      float bv;
      float* basep;
      if (m < 128) { bv = bout[m];        basep = out   + ((size_t)b * 128 + m) * NT; }
      else         { bv = bskip[m - 128]; basep = skipp + ((size_t)b * 256 + (m - 128)) * NT; }
      #pragma unroll
      for (int nf = 0; nf < 8; ++nf)
        basep[t0 + nf * 16 + l15] = am[nf][j] + bv;
    }
  }
}

extern "C" void kernel_launch(void* const* d_in, const int* in_sizes, int n_in,
                              void* d_out, int out_size, void* d_ws, size_t ws_size,
                              hipStream_t stream)
{
  const float* input = (const float*)d_in[0];
  const float* cond  = (const float*)d_in[1];
  const float* wconv = (const float*)d_in[2];
  const float* bconv = (const float*)d_in[3];
  const float* wcond = (const float*)d_in[4];
  const float* wout  = (const float*)d_in[5];
  const float* boutp = (const float*)d_in[6];
  const float* wskip = (const float*)d_in[7];
  const float* bskip = (const float*)d_in[8];
  float* out = (float*)d_out;

  unsigned short* wpc  = (unsigned short*)d_ws;     //  98304 elems
  unsigned short* wpcd = wpc + 98304;               //  24576 elems
  unsigned short* wp2  = wpcd + 24576;              //  49152 elems

  pack_weights<<<672, 256, 0, stream>>>(wconv, wcond, wout, wskip, wpc, wpcd, wp2);
  k12_fused<<<dim3(NT / TT, NB), 512, 0, stream>>>(wpc, wpcd, wp2, input, cond,
                                                   bconv, boutp, bskip, out);
}